// Round 1
// baseline (43.726 us; speedup 1.0000x reference)
//
#include <hip/hip_runtime.h>

// Anchor decode (YOLO-style), B=32, A=3, C=14 (7 box/conf + 7 cls), G=152.
// out[b, a2, gy, gx, f] (flattened (B, A*G*G, 15)):
//   f0=im  f1=re  f2=atan(im/re)  f3=sigmoid(conf)
//   f4=floor((sigmoid(tx)+gx)*4)  f5=floor((sigmoid(ty)+gy)*4)
//   f6=exp(tw)*anchor_w[a2]       f7=exp(th)*anchor_h[a2]
//   f8..14: cc=(f-8)*3+a2; src anchor as=cc/7, cls k=cc%7 -> x[b, as*14+7+k, gy, gx]
// (class channels deliberately scrambled across anchors — matches the
//  reshape(B,15,A,G,G) of the concatenated feats in the reference.)

constexpr int G   = 152;
constexpr int GG  = G * G;        // 23104, %4 == 0
constexpr int Cc  = 14;
constexpr int NTHREADS  = 256;
constexpr int TILE_ROWS = 1024;   // rows (=output 15-float groups) per block

__device__ __forceinline__ float sigmoidf_(float v) {
    return 1.0f / (1.0f + __expf(-v));
}
__device__ __forceinline__ float getc(const float4& v, int u) {
    switch (u) { case 0: return v.x; case 1: return v.y; case 2: return v.z; default: return v.w; }
}

__global__ __launch_bounds__(NTHREADS) void decode_kernel(
    const float* __restrict__ x, const float* __restrict__ anchors,
    float* __restrict__ out, int total_rows)
{
    // LDS: 1024 rows * 15 floats, padded: producer thread t owns words [t*61, t*61+60)
    __shared__ float lds[TILE_ROWS / 4 * 61];   // 15616 floats = 62464 B

    const int t  = threadIdx.x;
    const int r0 = blockIdx.x * TILE_ROWS + t * 4;   // 4 consecutive rows per thread

    if (r0 + 3 < total_rows) {
        const unsigned ba = (unsigned)r0 / (unsigned)GG;   // b*3 + a2 (same for all 4 rows)
        const int s0      = r0 - (int)ba * GG;             // %4 == 0
        const unsigned b  = ba / 3u;
        const int a2      = (int)(ba - b * 3u);
        const int gy      = s0 / G;
        const int gx0     = s0 - gy * G;                   // %4==0 -> no row wrap in the 4

        const float an_w = anchors[a2 * 2 + 0];
        const float an_h = anchors[a2 * 2 + 1];

        const float* xb = x + (size_t)(b * 42u) * GG + s0;
        const int cb = a2 * Cc;

        const float4 vtx = *(const float4*)(xb + (size_t)(cb + 0) * GG);
        const float4 vty = *(const float4*)(xb + (size_t)(cb + 1) * GG);
        const float4 vtw = *(const float4*)(xb + (size_t)(cb + 2) * GG);
        const float4 vth = *(const float4*)(xb + (size_t)(cb + 3) * GG);
        const float4 vim = *(const float4*)(xb + (size_t)(cb + 4) * GG);
        const float4 vre = *(const float4*)(xb + (size_t)(cb + 5) * GG);
        const float4 vcf = *(const float4*)(xb + (size_t)(cb + 6) * GG);
        float4 vcls[7];
#pragma unroll
        for (int fc = 0; fc < 7; ++fc) {
            const int cc = fc * 3 + a2;
            const int as = cc / 7;
            const int k  = cc - as * 7;
            vcls[fc] = *(const float4*)(xb + (size_t)(as * Cc + 7 + k) * GG);
        }

        float* wbase = lds + t * 61;
#pragma unroll
        for (int u = 0; u < 4; ++u) {
            const float im  = getc(vim, u);
            const float re  = getc(vre, u);
            const float yaw = atanf(im / re);
            const float cf  = sigmoidf_(getc(vcf, u));
            const float ax  = floorf((sigmoidf_(getc(vtx, u)) + (float)(gx0 + u)) * 4.0f);
            const float ay  = floorf((sigmoidf_(getc(vty, u)) + (float)gy) * 4.0f);
            const float aw  = __expf(getc(vtw, u)) * an_w;
            const float ah  = __expf(getc(vth, u)) * an_h;
            float* wb = wbase + u * 15;
            wb[0] = im; wb[1] = re; wb[2] = yaw; wb[3] = cf;
            wb[4] = ax; wb[5] = ay; wb[6] = aw; wb[7] = ah;
#pragma unroll
            for (int fc = 0; fc < 7; ++fc) wb[8 + fc] = getc(vcls[fc], u);
        }
    }
    __syncthreads();

    // Coalesced float4 store of the block's 15360-float chunk.
    const long long block_word0 = (long long)blockIdx.x * (TILE_ROWS * 15);
    const long long total_words = (long long)total_rows * 15;
    float* outp = out + block_word0;
#pragma unroll
    for (int i = 0; i < 15; ++i) {
        const int base = 4 * (i * NTHREADS + t);        // word offset within chunk, %4==0
        if (block_word0 + base + 3 < total_words) {
            const unsigned q = (unsigned)base / 60u;    // producer thread; same for all 4 words
            const float* rb = lds + base + q;
            float4 v;
            v.x = rb[0]; v.y = rb[1]; v.z = rb[2]; v.w = rb[3];
            *(float4*)(outp + base) = v;
        }
    }
}

extern "C" void kernel_launch(void* const* d_in, const int* in_sizes, int n_in,
                              void* d_out, int out_size, void* d_ws, size_t ws_size,
                              hipStream_t stream) {
    const float* x       = (const float*)d_in[0];
    const float* anchors = (const float*)d_in[1];
    float* out           = (float*)d_out;

    const int B          = in_sizes[0] / (3 * Cc * GG);   // 32
    const int total_rows = B * 3 * GG;                    // 2,217,984
    const int nblocks    = (total_rows + TILE_ROWS - 1) / TILE_ROWS;  // 2166

    hipLaunchKernelGGL(decode_kernel, dim3(nblocks), dim3(NTHREADS), 0, stream,
                       x, anchors, out, total_rows);
}